// Round 2
// baseline (41353.015 us; speedup 1.0000x reference)
//
#include <hip/hip_runtime.h>
#include <hip/hip_bf16.h>
#include <stdint.h>

#define T_LEN 1000
#define KIN   69
#define KIN_P 96
#define G3    1536
#define HDIM  512

typedef __attribute__((ext_vector_type(8))) short short8;
typedef __attribute__((ext_vector_type(4))) float f32x4;

#define MFMA(a,b,c) __builtin_amdgcn_mfma_f32_16x16x32_bf16((a),(b),(c),0,0,0)
#define AGENT __HIP_MEMORY_SCOPE_AGENT
#define SPIN_MAX 65536

static __device__ __forceinline__ float sigm(float x){ return 1.0f/(1.0f+__expf(-x)); }
static __device__ __forceinline__ float tanh_f(float x){
  float a = fabsf(x);
  float e = __expf(2.0f*a);
  float t = 1.0f - 2.0f/(e+1.0f);
  return x >= 0.0f ? t : -t;
}
static __device__ __forceinline__ unsigned short f2bf(float f){
  union { float f; unsigned int u; } v; v.f = f;
  unsigned int u = v.u;
  return (unsigned short)((u + 0x7fffu + ((u>>16)&1u)) >> 16);   // RNE
}
static __device__ __forceinline__ void wait_flag(unsigned int* flag, unsigned int target){
  int spins = 0;
  while (__hip_atomic_load(flag, __ATOMIC_RELAXED, AGENT) < target){
    __builtin_amdgcn_s_sleep(1);
    if (++spins > SPIN_MAX) break;      // hang-proof: bail with (wrong) data rather than wedge the GPU
  }
  __threadfence();                       // acquire: no h-load may be speculated above the spin exit
}

// ---------------- small converters ----------------
__global__ void k_conv(const float* __restrict__ src, unsigned short* __restrict__ dst, int n){
  int i = blockIdx.x*256 + threadIdx.x;
  if (i < n) dst[i] = f2bf(src[i]);
}
__global__ void k_conv_pad(const float* __restrict__ src, unsigned short* __restrict__ dst,
                           int rows, int ks, int kd){
  int i = blockIdx.x*256 + threadIdx.x;
  int r = i / kd, c = i % kd;
  if (r < rows) dst[i] = (c < ks) ? f2bf(src[r*ks + c]) : (unsigned short)0;
}
__global__ void k_sentinel(float* __restrict__ out, int n){
  int i = blockIdx.x*256 + threadIdx.x;
  if (i < n) out[i] = 1234.5f;
}

// x: [64][69][1000] f32  ->  xT: [(t*64+b)][96] bf16, zero-padded k 69..95
__global__ void k_xpose(const float* __restrict__ x, unsigned short* __restrict__ xT){
  int b = blockIdx.x & 63, tt = blockIdx.x >> 6;
  int t = tt*64 + threadIdx.x;
  if (t >= T_LEN) return;
  unsigned int* dst = (unsigned int*)(xT + (size_t)(t*64+b)*KIN_P);
  #pragma unroll
  for (int i=0;i<48;i++){
    int k0 = 2*i, k1 = 2*i+1;
    unsigned int lo = (k0<KIN) ? f2bf(x[((size_t)b*KIN + k0)*T_LEN + t]) : 0u;
    unsigned int hi = (k1<KIN) ? f2bf(x[((size_t)b*KIN + k1)*T_LEN + t]) : 0u;
    dst[i] = lo | (hi<<16);
  }
}

// ---------------- layer 0: fused input-proj + bidirectional recurrence ----------------
// grid = 32 blocks: dir = bid/16, slice n = bid%16 owns gate cols j in [32n, 32n+32)
#define NB_B 16
__launch_bounds__(512)
__global__ void k_gru0(const unsigned short* __restrict__ xT,
                       const unsigned short* __restrict__ whh0,  // [2][1536][512] bf16
                       const unsigned short* __restrict__ wih0,  // [2][1536][96]  bf16
                       const float* __restrict__ bih_f, const float* __restrict__ bhh_f,
                       const float* __restrict__ bih_b, const float* __restrict__ bhh_b,
                       unsigned short* __restrict__ l0out,       // [(t*64+b)][1024] bf16
                       unsigned int* __restrict__ hbuf,          // [2][2][64][256] dwords
                       unsigned int* __restrict__ flags)
{
  int bid = blockIdx.x;
  int dir = bid / NB_B;
  int n   = bid % NB_B;
  int j0  = n*32;
  int tid = threadIdx.x;
  int w = tid>>6, l = tid&63;
  int m0  = (w & 3) * 16;     // batch tile
  int h16 = w >> 2;           // j half of the 32-wide slice
  int lj = l & 15, lg = l >> 4;

  __shared__ unsigned char lds[96*1024 + 96*192];  // whh slice + wih slice (swizzled)
  unsigned char* whh_lds = lds;
  unsigned char* wih_lds = lds + 96*1024;
  const unsigned short* whh_g = whh0 + (size_t)dir*G3*HDIM;
  const unsigned short* wih_g = wih0 + (size_t)dir*G3*KIN_P;

  // stage whh slice: rows lr = g*32+jl -> global row g*512 + j0 + jl ; XOR-swizzle 16B cols
  for (int c = tid; c < 96*64; c += 512){
    int lr = c >> 6, c16 = c & 63;
    int g = lr >> 5, jl = lr & 31;
    int gr = g*512 + j0 + jl;
    uint4 v = *(const uint4*)(whh_g + (size_t)gr*HDIM + c16*8);
    *(uint4*)(whh_lds + lr*1024 + ((c16*16) ^ ((lr&7)<<4))) = v;
  }
  for (int c = tid; c < 96*12; c += 512){
    int lr = c / 12, c16 = c % 12;
    int g = lr >> 5, jl = lr & 31;
    int gr = g*512 + j0 + jl;
    uint4 v = *(const uint4*)(wih_g + (size_t)gr*KIN_P + c16*8);
    *(uint4*)(wih_lds + lr*192 + ((c16*16) ^ ((lr&3)<<4))) = v;
  }
  __syncthreads();

  int jl_mine = h16*16 + lj;       // 0..31 within slice
  int jg = j0 + jl_mine;           // 0..511 direction-local gate col
  const float* bih = dir ? bih_b : bih_f;
  const float* bhh = dir ? bhh_b : bhh_f;
  float brz = bih[jg] + bhh[jg];
  float bzz = bih[512+jg] + bhh[512+jg];
  float bxn = bih[1024+jg];
  float bhn = bhh[1024+jg];
  float hreg[4] = {0.f,0.f,0.f,0.f};
  unsigned int* hb   = hbuf  + (size_t)dir*2*64*256;
  unsigned int* flag = flags + dir*32;

  for (int ts = 0; ts < T_LEN; ts++){
    int t = dir ? (T_LEN-1-ts) : ts;
    f32x4 aR={0.f,0.f,0.f,0.f}, aZ={0.f,0.f,0.f,0.f}, aXN={0.f,0.f,0.f,0.f}, aHN={0.f,0.f,0.f,0.f};

    // ---- input-projection part (independent of h, overlaps the wait) ----
    const unsigned short* arow = xT + (size_t)(t*64 + m0 + lj)*KIN_P + lg*8;
    #pragma unroll
    for (int kt=0; kt<3; kt++){
      short8 a = *(const short8*)(arow + kt*32);
      int lr0 = 0*32 + jl_mine, lr1 = 1*32 + jl_mine, lr2 = 2*32 + jl_mine;
      int co = kt*64 + lg*16;
      short8 b0 = *(const short8*)(wih_lds + lr0*192 + (co ^ ((lr0&3)<<4)));
      short8 b1 = *(const short8*)(wih_lds + lr1*192 + (co ^ ((lr1&3)<<4)));
      short8 b2 = *(const short8*)(wih_lds + lr2*192 + (co ^ ((lr2&3)<<4)));
      aR  = MFMA(a, b0, aR);
      aZ  = MFMA(a, b1, aZ);
      aXN = MFMA(a, b2, aXN);
    }

    // ---- wait for h_ts from all producers of this direction ----
    if (ts > 0)
      wait_flag(flag, (unsigned int)(NB_B*8) * (unsigned int)ts);

    // ---- recurrent part: h (LLC-coherent loads) x whh slice ----
    unsigned int* hrow = hb + (ts&1)*64*256 + (m0+lj)*256 + lg*4;
    #pragma unroll
    for (int kt=0; kt<16; kt++){
      union { unsigned int u[4]; short8 s; } cv;
      cv.u[0] = __hip_atomic_load(hrow + kt*16 + 0, __ATOMIC_RELAXED, AGENT);
      cv.u[1] = __hip_atomic_load(hrow + kt*16 + 1, __ATOMIC_RELAXED, AGENT);
      cv.u[2] = __hip_atomic_load(hrow + kt*16 + 2, __ATOMIC_RELAXED, AGENT);
      cv.u[3] = __hip_atomic_load(hrow + kt*16 + 3, __ATOMIC_RELAXED, AGENT);
      int lr0 = 0*32 + jl_mine, lr1 = 1*32 + jl_mine, lr2 = 2*32 + jl_mine;
      int co = kt*64 + lg*16;
      short8 b0 = *(const short8*)(whh_lds + lr0*1024 + (co ^ ((lr0&7)<<4)));
      short8 b1 = *(const short8*)(whh_lds + lr1*1024 + (co ^ ((lr1&7)<<4)));
      short8 b2 = *(const short8*)(whh_lds + lr2*1024 + (co ^ ((lr2&7)<<4)));
      aR  = MFMA(cv.s, b0, aR);
      aZ  = MFMA(cv.s, b1, aZ);
      aHN = MFMA(cv.s, b2, aHN);
    }

    // ---- gates ----
    float hnew[4];
    #pragma unroll
    for (int i=0;i<4;i++){
      float r = sigm(aR[i] + brz);
      float z = sigm(aZ[i] + bzz);
      float nn = tanh_f(aXN[i] + bxn + r*(aHN[i] + bhn));
      hnew[i] = (1.0f - z)*nn + z*hreg[i];
      hreg[i] = hnew[i];
    }

    // ---- publish h_{ts+1}: pack j-pairs, agent-scope stores, then release-add ----
    unsigned int packed[4];
    #pragma unroll
    for (int i=0;i<4;i++){
      unsigned short mybf = f2bf(hnew[i]);
      unsigned short ot = (unsigned short)__shfl_xor((int)mybf, 1, 64);
      packed[i] = (unsigned int)mybf | ((unsigned int)ot << 16);
    }
    unsigned int* hw = hb + ((ts+1)&1)*64*256;
    if ((l & 1) == 0){
      #pragma unroll
      for (int i=0;i<4;i++){
        int b = m0 + lg*4 + i;
        __hip_atomic_store(hw + b*256 + (jg>>1), packed[i], __ATOMIC_RELAXED, AGENT);
      }
    }
    if (l == 0) __hip_atomic_fetch_add(flag, 1u, __ATOMIC_RELEASE, AGENT);

    // ---- layer-0 output (off critical path) ----
    #pragma unroll
    for (int i=0;i<4;i++){
      int b = m0 + lg*4 + i;
      l0out[(size_t)(t*64+b)*1024 + dir*512 + jg] = f2bf(hnew[i]);
    }
  }
}

// ---------------- layer 1: fused input-proj + fwd recurrence; bwd is ONE step ----------------
// grid = 64 blocks: bid<32 fwd recurrence slices (j0=16n), bid>=32 bwd single-step slices
__launch_bounds__(256)
__global__ void k_gru1(const unsigned short* __restrict__ l0out,
                       const unsigned short* __restrict__ wih1,   // [2][1536][1024] bf16 (f,b)
                       const unsigned short* __restrict__ whh1f,  // [1536][512] bf16
                       const float* __restrict__ bih_f, const float* __restrict__ bhh_f,
                       const float* __restrict__ bih_b, const float* __restrict__ bhh_b,
                       float* __restrict__ l1cat,                 // [64][1024] f32
                       unsigned int* __restrict__ hbuf,           // [2][64][256] dwords
                       unsigned int* __restrict__ flags)
{
  int bid = blockIdx.x;
  int bwd = bid >= 32;
  int n = bwd ? bid - 32 : bid;
  int j0 = n*16;
  int tid = threadIdx.x;
  int w = tid>>6, l = tid&63;
  int m0 = w*16, lj = l&15, lg = l>>4;

  __shared__ unsigned char lds[48*2048 + 48*1024];
  unsigned char* wih_lds = lds;
  unsigned char* whh_lds = lds + 48*2048;
  const unsigned short* wih_g = wih1 + (bwd ? (size_t)G3*1024 : 0);

  for (int c = tid; c < 48*128; c += 256){
    int lr = c >> 7, c16 = c & 127;
    int g = lr >> 4, jl = lr & 15;
    int gr = g*512 + j0 + jl;
    uint4 v = *(const uint4*)(wih_g + (size_t)gr*1024 + c16*8);
    *(uint4*)(wih_lds + lr*2048 + ((c16*16) ^ ((lr&7)<<4))) = v;
  }
  if (!bwd){
    for (int c = tid; c < 48*64; c += 256){
      int lr = c >> 6, c16 = c & 63;
      int g = lr >> 4, jl = lr & 15;
      int gr = g*512 + j0 + jl;
      uint4 v = *(const uint4*)(whh1f + (size_t)gr*HDIM + c16*8);
      *(uint4*)(whh_lds + lr*1024 + ((c16*16) ^ ((lr&7)<<4))) = v;
    }
  }
  __syncthreads();

  int jg = j0 + lj;
  const float* bih = bwd ? bih_b : bih_f;
  const float* bhh = bwd ? bhh_b : bhh_f;
  float brz = bih[jg] + bhh[jg];
  float bzz = bih[512+jg] + bhh[512+jg];
  float bxn = bih[1024+jg];
  float bhn = bhh[1024+jg];

  if (bwd){
    // single step at t=999 with h0 = 0  (gh = b_hh)
    int t = T_LEN-1;
    f32x4 aR={0.f,0.f,0.f,0.f}, aZ={0.f,0.f,0.f,0.f}, aXN={0.f,0.f,0.f,0.f};
    const unsigned short* arow = l0out + (size_t)(t*64 + m0 + lj)*1024 + lg*8;
    #pragma unroll 8
    for (int kt=0; kt<32; kt++){
      short8 a = *(const short8*)(arow + kt*32);
      int lr0 = 0*16+lj, lr1 = 1*16+lj, lr2 = 2*16+lj;
      int co = kt*64 + lg*16;
      short8 b0 = *(const short8*)(wih_lds + lr0*2048 + (co ^ ((lr0&7)<<4)));
      short8 b1 = *(const short8*)(wih_lds + lr1*2048 + (co ^ ((lr1&7)<<4)));
      short8 b2 = *(const short8*)(wih_lds + lr2*2048 + (co ^ ((lr2&7)<<4)));
      aR = MFMA(a,b0,aR); aZ = MFMA(a,b1,aZ); aXN = MFMA(a,b2,aXN);
    }
    #pragma unroll
    for (int i=0;i<4;i++){
      float r = sigm(aR[i] + brz);
      float z = sigm(aZ[i] + bzz);
      float nn = tanh_f(aXN[i] + bxn + r*bhn);
      l1cat[(size_t)(m0 + lg*4 + i)*1024 + 512 + jg] = (1.0f - z)*nn;
    }
    return;
  }

  float hreg[4] = {0.f,0.f,0.f,0.f};
  for (int ts = 0; ts < T_LEN; ts++){
    f32x4 aR={0.f,0.f,0.f,0.f}, aZ={0.f,0.f,0.f,0.f}, aXN={0.f,0.f,0.f,0.f}, aHN={0.f,0.f,0.f,0.f};
    const unsigned short* arow = l0out + (size_t)(ts*64 + m0 + lj)*1024 + lg*8;
    #pragma unroll 8
    for (int kt=0; kt<32; kt++){
      short8 a = *(const short8*)(arow + kt*32);
      int lr0 = 0*16+lj, lr1 = 1*16+lj, lr2 = 2*16+lj;
      int co = kt*64 + lg*16;
      short8 b0 = *(const short8*)(wih_lds + lr0*2048 + (co ^ ((lr0&7)<<4)));
      short8 b1 = *(const short8*)(wih_lds + lr1*2048 + (co ^ ((lr1&7)<<4)));
      short8 b2 = *(const short8*)(wih_lds + lr2*2048 + (co ^ ((lr2&7)<<4)));
      aR = MFMA(a,b0,aR); aZ = MFMA(a,b1,aZ); aXN = MFMA(a,b2,aXN);
    }
    if (ts > 0)
      wait_flag(flags, 128u * (unsigned int)ts);
    unsigned int* hrow = hbuf + (ts&1)*64*256 + (m0+lj)*256 + lg*4;
    #pragma unroll
    for (int kt=0; kt<16; kt++){
      union { unsigned int u[4]; short8 s; } cv;
      cv.u[0] = __hip_atomic_load(hrow + kt*16 + 0, __ATOMIC_RELAXED, AGENT);
      cv.u[1] = __hip_atomic_load(hrow + kt*16 + 1, __ATOMIC_RELAXED, AGENT);
      cv.u[2] = __hip_atomic_load(hrow + kt*16 + 2, __ATOMIC_RELAXED, AGENT);
      cv.u[3] = __hip_atomic_load(hrow + kt*16 + 3, __ATOMIC_RELAXED, AGENT);
      int lr0 = 0*16+lj, lr1 = 1*16+lj, lr2 = 2*16+lj;
      int co = kt*64 + lg*16;
      short8 b0 = *(const short8*)(whh_lds + lr0*1024 + (co ^ ((lr0&7)<<4)));
      short8 b1 = *(const short8*)(whh_lds + lr1*1024 + (co ^ ((lr1&7)<<4)));
      short8 b2 = *(const short8*)(whh_lds + lr2*1024 + (co ^ ((lr2&7)<<4)));
      aR = MFMA(cv.s,b0,aR); aZ = MFMA(cv.s,b1,aZ); aHN = MFMA(cv.s,b2,aHN);
    }
    float hnew[4];
    #pragma unroll
    for (int i=0;i<4;i++){
      float r = sigm(aR[i] + brz);
      float z = sigm(aZ[i] + bzz);
      float nn = tanh_f(aXN[i] + bxn + r*(aHN[i] + bhn));
      hnew[i] = (1.0f - z)*nn + z*hreg[i];
      hreg[i] = hnew[i];
    }
    if (ts < T_LEN-1){
      unsigned int packed[4];
      #pragma unroll
      for (int i=0;i<4;i++){
        unsigned short mybf = f2bf(hnew[i]);
        unsigned short ot = (unsigned short)__shfl_xor((int)mybf, 1, 64);
        packed[i] = (unsigned int)mybf | ((unsigned int)ot << 16);
      }
      unsigned int* hw = hbuf + ((ts+1)&1)*64*256;
      if ((l & 1) == 0){
        #pragma unroll
        for (int i=0;i<4;i++){
          int b = m0 + lg*4 + i;
          __hip_atomic_store(hw + b*256 + (jg>>1), packed[i], __ATOMIC_RELAXED, AGENT);
        }
      }
      if (l == 0) __hip_atomic_fetch_add(flags, 1u, __ATOMIC_RELEASE, AGENT);
    } else {
      #pragma unroll
      for (int i=0;i<4;i++)
        l1cat[(size_t)(m0 + lg*4 + i)*1024 + jg] = hnew[i];
    }
  }
}

// ---------------- final FC ----------------
__global__ void k_fc(const float* __restrict__ l1cat, const float* __restrict__ fcw,
                     const float* __restrict__ fcb, float* __restrict__ out){
  int idx = blockIdx.x*256 + threadIdx.x;
  if (idx >= 64*12) return;
  int b = idx / 12, o = idx % 12;
  float s = fcb[o];
  for (int k=0;k<1024;k++) s += l1cat[b*1024+k]*fcw[o*1024+k];
  out[idx] = s;
}

extern "C" void kernel_launch(void* const* d_in, const int* in_sizes, int n_in,
                              void* d_out, int out_size, void* d_ws, size_t ws_size,
                              hipStream_t stream){
  const float* x     = (const float*)d_in[0];
  const float* wih0f = (const float*)d_in[1];
  const float* whh0f = (const float*)d_in[2];
  const float* bih0f = (const float*)d_in[3];
  const float* bhh0f = (const float*)d_in[4];
  const float* wih0b = (const float*)d_in[5];
  const float* whh0b = (const float*)d_in[6];
  const float* bih0b = (const float*)d_in[7];
  const float* bhh0b = (const float*)d_in[8];
  const float* wih1f = (const float*)d_in[9];
  const float* whh1f = (const float*)d_in[10];
  const float* bih1f = (const float*)d_in[11];
  const float* bhh1f = (const float*)d_in[12];
  const float* wih1b = (const float*)d_in[13];
  const float* bih1b = (const float*)d_in[15];
  const float* bhh1b = (const float*)d_in[16];
  const float* fcw   = (const float*)d_in[17];
  const float* fcb   = (const float*)d_in[18];

  char* ws = (char*)d_ws;
  size_t off = 0;
  auto alloc = [&](size_t bytes)->void*{ void* p = ws + off; off = (off + bytes + 255) & ~(size_t)255; return p; };
  unsigned short* xT    = (unsigned short*)alloc((size_t)64000*96*2);
  unsigned short* whh0c = (unsigned short*)alloc((size_t)2*1536*512*2);
  unsigned short* wih0c = (unsigned short*)alloc((size_t)2*1536*96*2);
  unsigned short* wih1c = (unsigned short*)alloc((size_t)2*1536*1024*2);
  unsigned short* whh1c = (unsigned short*)alloc((size_t)1536*512*2);
  unsigned short* l0out = (unsigned short*)alloc((size_t)64000*1024*2);
  unsigned int*   hbB   = (unsigned int*)alloc((size_t)2*2*64*256*4);
  unsigned int*   hbD   = (unsigned int*)alloc((size_t)2*64*256*4);
  float*          l1cat = (float*)alloc((size_t)64*1024*4);
  unsigned int*   flg   = (unsigned int*)alloc(1024);

  if (off > ws_size){
    // workspace too small -> unambiguous sentinel instead of OOB writes
    k_sentinel<<<(out_size+255)/256,256,0,stream>>>((float*)d_out, out_size);
    return;
  }

  hipMemsetAsync(hbB, 0, (size_t)2*2*64*256*4, stream);
  hipMemsetAsync(hbD, 0, (size_t)2*64*256*4, stream);
  hipMemsetAsync(flg, 0, 1024, stream);

  k_conv<<<3072,256,0,stream>>>(whh0f, whh0c, 786432);
  k_conv<<<3072,256,0,stream>>>(whh0b, whh0c+786432, 786432);
  k_conv_pad<<<576,256,0,stream>>>(wih0f, wih0c, 1536, 69, 96);
  k_conv_pad<<<576,256,0,stream>>>(wih0b, wih0c+1536*96, 1536, 69, 96);
  k_conv<<<6144,256,0,stream>>>(wih1f, wih1c, 1572864);
  k_conv<<<6144,256,0,stream>>>(wih1b, wih1c+1572864, 1572864);
  k_conv<<<3072,256,0,stream>>>(whh1f, whh1c, 786432);
  k_xpose<<<1024,64,0,stream>>>(x, xT);

  k_gru0<<<32,512,0,stream>>>(xT, whh0c, wih0c, bih0f,bhh0f,bih0b,bhh0b, l0out, hbB, flg);
  k_gru1<<<64,256,0,stream>>>(l0out, wih1c, whh1c, bih1f,bhh1f,bih1b,bhh1b, l1cat, hbD, flg+64);
  k_fc<<<3,256,0,stream>>>(l1cat, fcw, fcb, (float*)d_out);
}

// Round 3
// 20978.752 us; speedup vs baseline: 1.9712x; 1.9712x over previous
//
#include <hip/hip_runtime.h>
#include <hip/hip_bf16.h>
#include <stdint.h>

#define T_LEN 1000
#define KIN   69
#define KIN_P 96
#define G3    1536
#define HDIM  512

typedef __attribute__((ext_vector_type(8))) short short8;
typedef __attribute__((ext_vector_type(4))) float f32x4;

#define MFMA(a,b,c) __builtin_amdgcn_mfma_f32_16x16x32_bf16((a),(b),(c),0,0,0)
#define AGENT __HIP_MEMORY_SCOPE_AGENT
#define SPIN_MAX 16384

static __device__ __forceinline__ float sigm(float x){ return 1.0f/(1.0f+__expf(-x)); }
static __device__ __forceinline__ float tanh_f(float x){
  float a = fabsf(x);
  float e = __expf(2.0f*a);
  float t = 1.0f - 2.0f/(e+1.0f);
  return x >= 0.0f ? t : -t;
}
static __device__ __forceinline__ unsigned short f2bf(float f){
  union { float f; unsigned int u; } v; v.f = f;
  unsigned int u = v.u;
  return (unsigned short)((u + 0x7fffu + ((u>>16)&1u)) >> 16);   // RNE
}
// t0-only: poll flag then acquire-fence. Other threads wait at the following __syncthreads().
static __device__ __forceinline__ void wait_flag(unsigned int* flag, unsigned int target){
  int spins = 0;
  while (__hip_atomic_load(flag, __ATOMIC_RELAXED, AGENT) < target){
    __builtin_amdgcn_s_sleep(2);
    if (++spins > SPIN_MAX) break;      // hang-proof: bail with wrong data rather than wedge the GPU
  }
  __threadfence();                       // acquire (t0 only): orders flag observation before h reads
}

// ---------------- small converters ----------------
__global__ void k_conv(const float* __restrict__ src, unsigned short* __restrict__ dst, int n){
  int i = blockIdx.x*256 + threadIdx.x;
  if (i < n) dst[i] = f2bf(src[i]);
}
__global__ void k_conv_pad(const float* __restrict__ src, unsigned short* __restrict__ dst,
                           int rows, int ks, int kd){
  int i = blockIdx.x*256 + threadIdx.x;
  int r = i / kd, c = i % kd;
  if (r < rows) dst[i] = (c < ks) ? f2bf(src[r*ks + c]) : (unsigned short)0;
}
__global__ void k_sentinel(float* __restrict__ out, int n){
  int i = blockIdx.x*256 + threadIdx.x;
  if (i < n) out[i] = 1234.5f;
}

// x: [64][69][1000] f32  ->  xT: [(t*64+b)][96] bf16, zero-padded k 69..95
__global__ void k_xpose(const float* __restrict__ x, unsigned short* __restrict__ xT){
  int b = blockIdx.x & 63, tt = blockIdx.x >> 6;
  int t = tt*64 + threadIdx.x;
  if (t >= T_LEN) return;
  unsigned int* dst = (unsigned int*)(xT + (size_t)(t*64+b)*KIN_P);
  #pragma unroll
  for (int i=0;i<48;i++){
    int k0 = 2*i, k1 = 2*i+1;
    unsigned int lo = (k0<KIN) ? f2bf(x[((size_t)b*KIN + k0)*T_LEN + t]) : 0u;
    unsigned int hi = (k1<KIN) ? f2bf(x[((size_t)b*KIN + k1)*T_LEN + t]) : 0u;
    dst[i] = lo | (hi<<16);
  }
}

// ---------------- layer 0: fused input-proj + bidirectional recurrence ----------------
// grid = 32 blocks: dir = bid/16, slice n = bid%16 owns gate cols j in [32n, 32n+32)
#define NB_B 16
__launch_bounds__(512)
__global__ void k_gru0(const unsigned short* __restrict__ xT,
                       const unsigned short* __restrict__ whh0,  // [2][1536][512] bf16
                       const unsigned short* __restrict__ wih0,  // [2][1536][96]  bf16
                       const float* __restrict__ bih_f, const float* __restrict__ bhh_f,
                       const float* __restrict__ bih_b, const float* __restrict__ bhh_b,
                       unsigned short* __restrict__ l0out,       // [(t*64+b)][1024] bf16
                       unsigned int* __restrict__ hbuf,          // [2][2][64][256] dwords
                       unsigned int* __restrict__ flags)
{
  int bid = blockIdx.x;
  int dir = bid / NB_B;
  int n   = bid % NB_B;
  int j0  = n*32;
  int tid = threadIdx.x;
  int w = tid>>6, l = tid&63;
  int m0  = (w & 3) * 16;     // batch tile
  int h16 = w >> 2;           // j half of the 32-wide slice
  int lj = l & 15, lg = l >> 4;

  __shared__ unsigned char lds[96*1024 + 96*192];  // whh slice + wih slice (swizzled)
  unsigned char* whh_lds = lds;
  unsigned char* wih_lds = lds + 96*1024;
  const unsigned short* whh_g = whh0 + (size_t)dir*G3*HDIM;
  const unsigned short* wih_g = wih0 + (size_t)dir*G3*KIN_P;

  // stage whh slice: rows lr = g*32+jl -> global row g*512 + j0 + jl ; XOR-swizzle 16B cols
  for (int c = tid; c < 96*64; c += 512){
    int lr = c >> 6, c16 = c & 63;
    int g = lr >> 5, jl = lr & 31;
    int gr = g*512 + j0 + jl;
    uint4 v = *(const uint4*)(whh_g + (size_t)gr*HDIM + c16*8);
    *(uint4*)(whh_lds + lr*1024 + ((c16*16) ^ ((lr&7)<<4))) = v;
  }
  for (int c = tid; c < 96*12; c += 512){
    int lr = c / 12, c16 = c % 12;
    int g = lr >> 5, jl = lr & 31;
    int gr = g*512 + j0 + jl;
    uint4 v = *(const uint4*)(wih_g + (size_t)gr*KIN_P + c16*8);
    *(uint4*)(wih_lds + lr*192 + ((c16*16) ^ ((lr&3)<<4))) = v;
  }
  __syncthreads();

  int jl_mine = h16*16 + lj;       // 0..31 within slice
  int jg = j0 + jl_mine;           // 0..511 direction-local gate col
  const float* bih = dir ? bih_b : bih_f;
  const float* bhh = dir ? bhh_b : bhh_f;
  float brz = bih[jg] + bhh[jg];
  float bzz = bih[512+jg] + bhh[512+jg];
  float bxn = bih[1024+jg];
  float bhn = bhh[1024+jg];
  float hreg[4] = {0.f,0.f,0.f,0.f};
  unsigned int* hb   = hbuf  + (size_t)dir*2*64*256;
  unsigned int* flag = flags + dir*32;

  for (int ts = 0; ts < T_LEN; ts++){
    int t = dir ? (T_LEN-1-ts) : ts;
    f32x4 aR={0.f,0.f,0.f,0.f}, aZ={0.f,0.f,0.f,0.f}, aXN={0.f,0.f,0.f,0.f}, aHN={0.f,0.f,0.f,0.f};

    // ---- input-projection part (independent of h, overlaps the wait) ----
    const unsigned short* arow = xT + (size_t)(t*64 + m0 + lj)*KIN_P + lg*8;
    #pragma unroll
    for (int kt=0; kt<3; kt++){
      short8 a = *(const short8*)(arow + kt*32);
      int lr0 = 0*32 + jl_mine, lr1 = 1*32 + jl_mine, lr2 = 2*32 + jl_mine;
      int co = kt*64 + lg*16;
      short8 b0 = *(const short8*)(wih_lds + lr0*192 + (co ^ ((lr0&3)<<4)));
      short8 b1 = *(const short8*)(wih_lds + lr1*192 + (co ^ ((lr1&3)<<4)));
      short8 b2 = *(const short8*)(wih_lds + lr2*192 + (co ^ ((lr2&3)<<4)));
      aR  = MFMA(a, b0, aR);
      aZ  = MFMA(a, b1, aZ);
      aXN = MFMA(a, b2, aXN);
    }

    // ---- wait for h_ts from all producers of this direction (t0 polls, rest park at barrier) ----
    if (ts > 0){
      if (tid == 0) wait_flag(flag, (unsigned int)NB_B * (unsigned int)ts);
      __syncthreads();
    }

    // ---- recurrent part: h (LLC-coherent 8B loads) x whh slice ----
    const unsigned long long* hrow = (const unsigned long long*)hb
        + (((ts&1)*64*256 + (m0+lj)*256 + lg*4) >> 1);
    #pragma unroll
    for (int kt=0; kt<16; kt++){
      union { unsigned long long u[2]; short8 s; } cv;
      cv.u[0] = __hip_atomic_load(hrow + kt*8 + 0, __ATOMIC_RELAXED, AGENT);
      cv.u[1] = __hip_atomic_load(hrow + kt*8 + 1, __ATOMIC_RELAXED, AGENT);
      int lr0 = 0*32 + jl_mine, lr1 = 1*32 + jl_mine, lr2 = 2*32 + jl_mine;
      int co = kt*64 + lg*16;
      short8 b0 = *(const short8*)(whh_lds + lr0*1024 + (co ^ ((lr0&7)<<4)));
      short8 b1 = *(const short8*)(whh_lds + lr1*1024 + (co ^ ((lr1&7)<<4)));
      short8 b2 = *(const short8*)(whh_lds + lr2*1024 + (co ^ ((lr2&7)<<4)));
      aR  = MFMA(cv.s, b0, aR);
      aZ  = MFMA(cv.s, b1, aZ);
      aHN = MFMA(cv.s, b2, aHN);
    }

    // ---- gates ----
    float hnew[4];
    #pragma unroll
    for (int i=0;i<4;i++){
      float r = sigm(aR[i] + brz);
      float z = sigm(aZ[i] + bzz);
      float nn = tanh_f(aXN[i] + bxn + r*(aHN[i] + bhn));
      hnew[i] = (1.0f - z)*nn + z*hreg[i];
      hreg[i] = hnew[i];
    }

    // ---- publish h_{ts+1}: pack j-pairs, agent-scope stores; barrier drains, t0 releases ----
    unsigned int packed[4];
    #pragma unroll
    for (int i=0;i<4;i++){
      unsigned short mybf = f2bf(hnew[i]);
      unsigned short ot = (unsigned short)__shfl_xor((int)mybf, 1, 64);
      packed[i] = (unsigned int)mybf | ((unsigned int)ot << 16);
    }
    unsigned int* hw = hb + ((ts+1)&1)*64*256;
    if ((l & 1) == 0){
      #pragma unroll
      for (int i=0;i<4;i++){
        int b = m0 + lg*4 + i;
        __hip_atomic_store(hw + b*256 + (jg>>1), packed[i], __ATOMIC_RELAXED, AGENT);
      }
    }
    __syncthreads();                       // drains vmcnt for all waves' h-stores
    if (tid == 0) __hip_atomic_fetch_add(flag, 1u, __ATOMIC_RELEASE, AGENT);

    // ---- layer-0 output (off critical path, after the release) ----
    #pragma unroll
    for (int i=0;i<4;i++){
      int b = m0 + lg*4 + i;
      l0out[(size_t)(t*64+b)*1024 + dir*512 + jg] = f2bf(hnew[i]);
    }
  }
}

// ---------------- layer 1: fused input-proj + fwd recurrence; bwd is ONE step ----------------
// grid = 64 blocks: bid<32 fwd recurrence slices (j0=16n), bid>=32 bwd single-step slices
__launch_bounds__(256)
__global__ void k_gru1(const unsigned short* __restrict__ l0out,
                       const unsigned short* __restrict__ wih1,   // [2][1536][1024] bf16 (f,b)
                       const unsigned short* __restrict__ whh1f,  // [1536][512] bf16
                       const float* __restrict__ bih_f, const float* __restrict__ bhh_f,
                       const float* __restrict__ bih_b, const float* __restrict__ bhh_b,
                       float* __restrict__ l1cat,                 // [64][1024] f32
                       unsigned int* __restrict__ hbuf,           // [2][64][256] dwords
                       unsigned int* __restrict__ flags)
{
  int bid = blockIdx.x;
  int bwd = bid >= 32;
  int n = bwd ? bid - 32 : bid;
  int j0 = n*16;
  int tid = threadIdx.x;
  int w = tid>>6, l = tid&63;
  int m0 = w*16, lj = l&15, lg = l>>4;

  __shared__ unsigned char lds[48*2048 + 48*1024];
  unsigned char* wih_lds = lds;
  unsigned char* whh_lds = lds + 48*2048;
  const unsigned short* wih_g = wih1 + (bwd ? (size_t)G3*1024 : 0);

  for (int c = tid; c < 48*128; c += 256){
    int lr = c >> 7, c16 = c & 127;
    int g = lr >> 4, jl = lr & 15;
    int gr = g*512 + j0 + jl;
    uint4 v = *(const uint4*)(wih_g + (size_t)gr*1024 + c16*8);
    *(uint4*)(wih_lds + lr*2048 + ((c16*16) ^ ((lr&7)<<4))) = v;
  }
  if (!bwd){
    for (int c = tid; c < 48*64; c += 256){
      int lr = c >> 6, c16 = c & 63;
      int g = lr >> 4, jl = lr & 15;
      int gr = g*512 + j0 + jl;
      uint4 v = *(const uint4*)(whh1f + (size_t)gr*HDIM + c16*8);
      *(uint4*)(whh_lds + lr*1024 + ((c16*16) ^ ((lr&7)<<4))) = v;
    }
  }
  __syncthreads();

  int jg = j0 + lj;
  const float* bih = bwd ? bih_b : bih_f;
  const float* bhh = bwd ? bhh_b : bhh_f;
  float brz = bih[jg] + bhh[jg];
  float bzz = bih[512+jg] + bhh[512+jg];
  float bxn = bih[1024+jg];
  float bhn = bhh[1024+jg];

  if (bwd){
    // single step at t=999 with h0 = 0  (gh = b_hh)
    int t = T_LEN-1;
    f32x4 aR={0.f,0.f,0.f,0.f}, aZ={0.f,0.f,0.f,0.f}, aXN={0.f,0.f,0.f,0.f};
    const unsigned short* arow = l0out + (size_t)(t*64 + m0 + lj)*1024 + lg*8;
    #pragma unroll 8
    for (int kt=0; kt<32; kt++){
      short8 a = *(const short8*)(arow + kt*32);
      int lr0 = 0*16+lj, lr1 = 1*16+lj, lr2 = 2*16+lj;
      int co = kt*64 + lg*16;
      short8 b0 = *(const short8*)(wih_lds + lr0*2048 + (co ^ ((lr0&7)<<4)));
      short8 b1 = *(const short8*)(wih_lds + lr1*2048 + (co ^ ((lr1&7)<<4)));
      short8 b2 = *(const short8*)(wih_lds + lr2*2048 + (co ^ ((lr2&7)<<4)));
      aR = MFMA(a,b0,aR); aZ = MFMA(a,b1,aZ); aXN = MFMA(a,b2,aXN);
    }
    #pragma unroll
    for (int i=0;i<4;i++){
      float r = sigm(aR[i] + brz);
      float z = sigm(aZ[i] + bzz);
      float nn = tanh_f(aXN[i] + bxn + r*bhn);
      l1cat[(size_t)(m0 + lg*4 + i)*1024 + 512 + jg] = (1.0f - z)*nn;
    }
    return;
  }

  float hreg[4] = {0.f,0.f,0.f,0.f};
  for (int ts = 0; ts < T_LEN; ts++){
    f32x4 aR={0.f,0.f,0.f,0.f}, aZ={0.f,0.f,0.f,0.f}, aXN={0.f,0.f,0.f,0.f}, aHN={0.f,0.f,0.f,0.f};
    const unsigned short* arow = l0out + (size_t)(ts*64 + m0 + lj)*1024 + lg*8;
    #pragma unroll 8
    for (int kt=0; kt<32; kt++){
      short8 a = *(const short8*)(arow + kt*32);
      int lr0 = 0*16+lj, lr1 = 1*16+lj, lr2 = 2*16+lj;
      int co = kt*64 + lg*16;
      short8 b0 = *(const short8*)(wih_lds + lr0*2048 + (co ^ ((lr0&7)<<4)));
      short8 b1 = *(const short8*)(wih_lds + lr1*2048 + (co ^ ((lr1&7)<<4)));
      short8 b2 = *(const short8*)(wih_lds + lr2*2048 + (co ^ ((lr2&7)<<4)));
      aR = MFMA(a,b0,aR); aZ = MFMA(a,b1,aZ); aXN = MFMA(a,b2,aXN);
    }
    if (ts > 0){
      if (tid == 0) wait_flag(flags, 32u * (unsigned int)ts);
      __syncthreads();
    }
    const unsigned long long* hrow = (const unsigned long long*)hbuf
        + (((ts&1)*64*256 + (m0+lj)*256 + lg*4) >> 1);
    #pragma unroll
    for (int kt=0; kt<16; kt++){
      union { unsigned long long u[2]; short8 s; } cv;
      cv.u[0] = __hip_atomic_load(hrow + kt*8 + 0, __ATOMIC_RELAXED, AGENT);
      cv.u[1] = __hip_atomic_load(hrow + kt*8 + 1, __ATOMIC_RELAXED, AGENT);
      int lr0 = 0*16+lj, lr1 = 1*16+lj, lr2 = 2*16+lj;
      int co = kt*64 + lg*16;
      short8 b0 = *(const short8*)(whh_lds + lr0*1024 + (co ^ ((lr0&7)<<4)));
      short8 b1 = *(const short8*)(whh_lds + lr1*1024 + (co ^ ((lr1&7)<<4)));
      short8 b2 = *(const short8*)(whh_lds + lr2*1024 + (co ^ ((lr2&7)<<4)));
      aR = MFMA(cv.s,b0,aR); aZ = MFMA(cv.s,b1,aZ); aHN = MFMA(cv.s,b2,aHN);
    }
    float hnew[4];
    #pragma unroll
    for (int i=0;i<4;i++){
      float r = sigm(aR[i] + brz);
      float z = sigm(aZ[i] + bzz);
      float nn = tanh_f(aXN[i] + bxn + r*(aHN[i] + bhn));
      hnew[i] = (1.0f - z)*nn + z*hreg[i];
      hreg[i] = hnew[i];
    }
    if (ts < T_LEN-1){
      unsigned int packed[4];
      #pragma unroll
      for (int i=0;i<4;i++){
        unsigned short mybf = f2bf(hnew[i]);
        unsigned short ot = (unsigned short)__shfl_xor((int)mybf, 1, 64);
        packed[i] = (unsigned int)mybf | ((unsigned int)ot << 16);
      }
      unsigned int* hw = hbuf + ((ts+1)&1)*64*256;
      if ((l & 1) == 0){
        #pragma unroll
        for (int i=0;i<4;i++){
          int b = m0 + lg*4 + i;
          __hip_atomic_store(hw + b*256 + (jg>>1), packed[i], __ATOMIC_RELAXED, AGENT);
        }
      }
      __syncthreads();
      if (tid == 0) __hip_atomic_fetch_add(flags, 1u, __ATOMIC_RELEASE, AGENT);
    } else {
      #pragma unroll
      for (int i=0;i<4;i++)
        l1cat[(size_t)(m0 + lg*4 + i)*1024 + jg] = hnew[i];
    }
  }
}

// ---------------- final FC ----------------
__global__ void k_fc(const float* __restrict__ l1cat, const float* __restrict__ fcw,
                     const float* __restrict__ fcb, float* __restrict__ out){
  int idx = blockIdx.x*256 + threadIdx.x;
  if (idx >= 64*12) return;
  int b = idx / 12, o = idx % 12;
  float s = fcb[o];
  for (int k=0;k<1024;k++) s += l1cat[b*1024+k]*fcw[o*1024+k];
  out[idx] = s;
}

extern "C" void kernel_launch(void* const* d_in, const int* in_sizes, int n_in,
                              void* d_out, int out_size, void* d_ws, size_t ws_size,
                              hipStream_t stream){
  const float* x     = (const float*)d_in[0];
  const float* wih0f = (const float*)d_in[1];
  const float* whh0f = (const float*)d_in[2];
  const float* bih0f = (const float*)d_in[3];
  const float* bhh0f = (const float*)d_in[4];
  const float* wih0b = (const float*)d_in[5];
  const float* whh0b = (const float*)d_in[6];
  const float* bih0b = (const float*)d_in[7];
  const float* bhh0b = (const float*)d_in[8];
  const float* wih1f = (const float*)d_in[9];
  const float* whh1f = (const float*)d_in[10];
  const float* bih1f = (const float*)d_in[11];
  const float* bhh1f = (const float*)d_in[12];
  const float* wih1b = (const float*)d_in[13];
  const float* bih1b = (const float*)d_in[15];
  const float* bhh1b = (const float*)d_in[16];
  const float* fcw   = (const float*)d_in[17];
  const float* fcb   = (const float*)d_in[18];

  char* ws = (char*)d_ws;
  size_t off = 0;
  auto alloc = [&](size_t bytes)->void*{ void* p = ws + off; off = (off + bytes + 255) & ~(size_t)255; return p; };
  unsigned short* xT    = (unsigned short*)alloc((size_t)64000*96*2);
  unsigned short* whh0c = (unsigned short*)alloc((size_t)2*1536*512*2);
  unsigned short* wih0c = (unsigned short*)alloc((size_t)2*1536*96*2);
  unsigned short* wih1c = (unsigned short*)alloc((size_t)2*1536*1024*2);
  unsigned short* whh1c = (unsigned short*)alloc((size_t)1536*512*2);
  unsigned short* l0out = (unsigned short*)alloc((size_t)64000*1024*2);
  unsigned int*   hbB   = (unsigned int*)alloc((size_t)2*2*64*256*4);
  unsigned int*   hbD   = (unsigned int*)alloc((size_t)2*64*256*4);
  float*          l1cat = (float*)alloc((size_t)64*1024*4);
  unsigned int*   flg   = (unsigned int*)alloc(1024);

  if (off > ws_size){
    // workspace too small -> unambiguous sentinel instead of OOB writes
    k_sentinel<<<(out_size+255)/256,256,0,stream>>>((float*)d_out, out_size);
    return;
  }

  hipMemsetAsync(hbB, 0, (size_t)2*2*64*256*4, stream);
  hipMemsetAsync(hbD, 0, (size_t)2*64*256*4, stream);
  hipMemsetAsync(flg, 0, 1024, stream);

  k_conv<<<3072,256,0,stream>>>(whh0f, whh0c, 786432);
  k_conv<<<3072,256,0,stream>>>(whh0b, whh0c+786432, 786432);
  k_conv_pad<<<576,256,0,stream>>>(wih0f, wih0c, 1536, 69, 96);
  k_conv_pad<<<576,256,0,stream>>>(wih0b, wih0c+1536*96, 1536, 69, 96);
  k_conv<<<6144,256,0,stream>>>(wih1f, wih1c, 1572864);
  k_conv<<<6144,256,0,stream>>>(wih1b, wih1c+1572864, 1572864);
  k_conv<<<3072,256,0,stream>>>(whh1f, whh1c, 786432);
  k_xpose<<<1024,64,0,stream>>>(x, xT);

  k_gru0<<<32,512,0,stream>>>(xT, whh0c, wih0c, bih0f,bhh0f,bih0b,bhh0b, l0out, hbB, flg);
  k_gru1<<<64,256,0,stream>>>(l0out, wih1c, whh1c, bih1f,bhh1f,bih1b,bhh1b, l1cat, hbD, flg+64);
  k_fc<<<3,256,0,stream>>>(l1cat, fcw, fcb, (float*)d_out);
}

// Round 4
// 19080.191 us; speedup vs baseline: 2.1673x; 1.0995x over previous
//
#include <hip/hip_runtime.h>
#include <hip/hip_bf16.h>
#include <stdint.h>

#define T_LEN 1000
#define KIN   69
#define KIN_P 96
#define G3    1536
#define HDIM  512

typedef __attribute__((ext_vector_type(8))) short short8;
typedef __attribute__((ext_vector_type(4))) float f32x4;

#define MFMA(a,b,c) __builtin_amdgcn_mfma_f32_16x16x32_bf16((a),(b),(c),0,0,0)
#define AGENT __HIP_MEMORY_SCOPE_AGENT
#define WG    __HIP_MEMORY_SCOPE_WORKGROUP
#define SPIN_MAX 32768

static __device__ __forceinline__ float sigm(float x){ return 1.0f/(1.0f+__expf(-x)); }
static __device__ __forceinline__ float tanh_f(float x){
  float a = fabsf(x);
  float e = __expf(2.0f*a);
  float t = 1.0f - 2.0f/(e+1.0f);
  return x >= 0.0f ? t : -t;
}
static __device__ __forceinline__ unsigned short f2bf(float f){
  union { float f; unsigned int u; } v; v.f = f;
  unsigned int u = v.u;
  return (unsigned short)((u + 0x7fffu + ((u>>16)&1u)) >> 16);   // RNE
}

// Wave-0 parallel wait: lane i polls producer i's slot (128B apart) with relaxed
// agent loads (LLC-served). Exit when all slots >= target. Then one cheap
// workgroup-scope ACQUIRE load for compiler/issue ordering — NO L2 invalidate.
// h data loads are agent-scope (sc0+sc1, LLC-served), so flag-then-data causality
// at the LLC guarantees freshness without invalidating L2.
static __device__ __forceinline__ void wave0_wait(const unsigned int* slots, int np,
                                                  unsigned int target, int lane){
  bool passive = lane >= np;
  int spins = 0;
  for(;;){
    bool d = passive ||
      (__hip_atomic_load(slots + lane*32, __ATOMIC_RELAXED, AGENT) >= target);
    if (__all((int)d)) break;
    if (++spins > SPIN_MAX) break;      // hang-proof bail
  }
  (void)__hip_atomic_load(slots, __ATOMIC_ACQUIRE, WG);
}

// ---------------- small converters ----------------
__global__ void k_conv(const float* __restrict__ src, unsigned short* __restrict__ dst, int n){
  int i = blockIdx.x*256 + threadIdx.x;
  if (i < n) dst[i] = f2bf(src[i]);
}
__global__ void k_conv_pad(const float* __restrict__ src, unsigned short* __restrict__ dst,
                           int rows, int ks, int kd){
  int i = blockIdx.x*256 + threadIdx.x;
  int r = i / kd, c = i % kd;
  if (r < rows) dst[i] = (c < ks) ? f2bf(src[r*ks + c]) : (unsigned short)0;
}
__global__ void k_sentinel(float* __restrict__ out, int n){
  int i = blockIdx.x*256 + threadIdx.x;
  if (i < n) out[i] = 1234.5f;
}

// x: [64][69][1000] f32  ->  xT: [(t*64+b)][96] bf16, zero-padded k 69..95
__global__ void k_xpose(const float* __restrict__ x, unsigned short* __restrict__ xT){
  int b = blockIdx.x & 63, tt = blockIdx.x >> 6;
  int t = tt*64 + threadIdx.x;
  if (t >= T_LEN) return;
  unsigned int* dst = (unsigned int*)(xT + (size_t)(t*64+b)*KIN_P);
  #pragma unroll
  for (int i=0;i<48;i++){
    int k0 = 2*i, k1 = 2*i+1;
    unsigned int lo = (k0<KIN) ? f2bf(x[((size_t)b*KIN + k0)*T_LEN + t]) : 0u;
    unsigned int hi = (k1<KIN) ? f2bf(x[((size_t)b*KIN + k1)*T_LEN + t]) : 0u;
    dst[i] = lo | (hi<<16);
  }
}

// ---------------- layer 0: fused input-proj + bidirectional recurrence ----------------
// grid = 32 blocks: dir = bid/16, slice n = bid%16 owns gate cols j in [32n, 32n+32)
#define NB_B 16
__launch_bounds__(512)
__global__ void k_gru0(const unsigned short* __restrict__ xT,
                       const unsigned short* __restrict__ whh0,  // [2][1536][512] bf16
                       const unsigned short* __restrict__ wih0,  // [2][1536][96]  bf16
                       const float* __restrict__ bih_f, const float* __restrict__ bhh_f,
                       const float* __restrict__ bih_b, const float* __restrict__ bhh_b,
                       unsigned short* __restrict__ l0out,       // [(t*64+b)][1024] bf16
                       unsigned int* __restrict__ hbuf,          // [2][2][64][256] dwords
                       unsigned int* __restrict__ flags)         // 64 slots x 32 dwords
{
  int bid = blockIdx.x;
  int dir = bid / NB_B;
  int n   = bid % NB_B;
  int j0  = n*32;
  int tid = threadIdx.x;
  int w = tid>>6, l = tid&63;
  int m0  = (w & 3) * 16;     // batch tile
  int h16 = w >> 2;           // j half of the 32-wide slice
  int lj = l & 15, lg = l >> 4;

  __shared__ unsigned char lds[96*1024 + 96*192];  // whh slice + wih slice (swizzled)
  unsigned char* whh_lds = lds;
  unsigned char* wih_lds = lds + 96*1024;
  const unsigned short* whh_g = whh0 + (size_t)dir*G3*HDIM;
  const unsigned short* wih_g = wih0 + (size_t)dir*G3*KIN_P;

  // stage whh slice: rows lr = g*32+jl -> global row g*512 + j0 + jl ; XOR-swizzle 16B cols
  for (int c = tid; c < 96*64; c += 512){
    int lr = c >> 6, c16 = c & 63;
    int g = lr >> 5, jl = lr & 31;
    int gr = g*512 + j0 + jl;
    uint4 v = *(const uint4*)(whh_g + (size_t)gr*HDIM + c16*8);
    *(uint4*)(whh_lds + lr*1024 + ((c16*16) ^ ((lr&7)<<4))) = v;
  }
  for (int c = tid; c < 96*12; c += 512){
    int lr = c / 12, c16 = c % 12;
    int g = lr >> 5, jl = lr & 31;
    int gr = g*512 + j0 + jl;
    uint4 v = *(const uint4*)(wih_g + (size_t)gr*KIN_P + c16*8);
    *(uint4*)(wih_lds + lr*192 + ((c16*16) ^ ((lr&3)<<4))) = v;
  }
  __syncthreads();

  int jl_mine = h16*16 + lj;       // 0..31 within slice
  int jg = j0 + jl_mine;           // 0..511 direction-local gate col
  const float* bih = dir ? bih_b : bih_f;
  const float* bhh = dir ? bhh_b : bhh_f;
  float brz = bih[jg] + bhh[jg];
  float bzz = bih[512+jg] + bhh[512+jg];
  float bxn = bih[1024+jg];
  float bhn = bhh[1024+jg];
  float hreg[4] = {0.f,0.f,0.f,0.f};
  unsigned int* hb    = hbuf  + (size_t)dir*2*64*256;
  unsigned int* fbase = flags + dir*NB_B*32;      // this direction's 16 producer slots
  unsigned int* fmine = fbase + n*32;

  for (int ts = 0; ts < T_LEN; ts++){
    int t = dir ? (T_LEN-1-ts) : ts;
    f32x4 aR={0.f,0.f,0.f,0.f}, aZ={0.f,0.f,0.f,0.f}, aXN={0.f,0.f,0.f,0.f}, aHN={0.f,0.f,0.f,0.f};

    // ---- input-projection part (independent of h, overlaps the wait) ----
    const unsigned short* arow = xT + (size_t)(t*64 + m0 + lj)*KIN_P + lg*8;
    #pragma unroll
    for (int kt=0; kt<3; kt++){
      short8 a = *(const short8*)(arow + kt*32);
      int lr0 = 0*32 + jl_mine, lr1 = 1*32 + jl_mine, lr2 = 2*32 + jl_mine;
      int co = kt*64 + lg*16;
      short8 b0 = *(const short8*)(wih_lds + lr0*192 + (co ^ ((lr0&3)<<4)));
      short8 b1 = *(const short8*)(wih_lds + lr1*192 + (co ^ ((lr1&3)<<4)));
      short8 b2 = *(const short8*)(wih_lds + lr2*192 + (co ^ ((lr2&3)<<4)));
      aR  = MFMA(a, b0, aR);
      aZ  = MFMA(a, b1, aZ);
      aXN = MFMA(a, b2, aXN);
    }

    // ---- wait for h_ts from all producers of this direction ----
    if (ts > 0){
      if (w == 0) wave0_wait(fbase, NB_B, (unsigned int)ts, l);
      __syncthreads();
    }

    // ---- recurrent part: h (LLC-served 8B loads) x whh slice ----
    const unsigned long long* hrow = (const unsigned long long*)hb
        + (((ts&1)*64*256 + (m0+lj)*256 + lg*4) >> 1);
    #pragma unroll
    for (int kt=0; kt<16; kt++){
      union { unsigned long long u[2]; short8 s; } cv;
      cv.u[0] = __hip_atomic_load(hrow + kt*8 + 0, __ATOMIC_RELAXED, AGENT);
      cv.u[1] = __hip_atomic_load(hrow + kt*8 + 1, __ATOMIC_RELAXED, AGENT);
      int lr0 = 0*32 + jl_mine, lr1 = 1*32 + jl_mine, lr2 = 2*32 + jl_mine;
      int co = kt*64 + lg*16;
      short8 b0 = *(const short8*)(whh_lds + lr0*1024 + (co ^ ((lr0&7)<<4)));
      short8 b1 = *(const short8*)(whh_lds + lr1*1024 + (co ^ ((lr1&7)<<4)));
      short8 b2 = *(const short8*)(whh_lds + lr2*1024 + (co ^ ((lr2&7)<<4)));
      aR  = MFMA(cv.s, b0, aR);
      aZ  = MFMA(cv.s, b1, aZ);
      aHN = MFMA(cv.s, b2, aHN);
    }

    // ---- gates ----
    float hnew[4];
    #pragma unroll
    for (int i=0;i<4;i++){
      float r = sigm(aR[i] + brz);
      float z = sigm(aZ[i] + bzz);
      float nn = tanh_f(aXN[i] + bxn + r*(aHN[i] + bhn));
      hnew[i] = (1.0f - z)*nn + z*hreg[i];
      hreg[i] = hnew[i];
    }

    // ---- publish h_{ts+1}: agent stores; barrier drains vmcnt; t0 stores own slot ----
    unsigned int packed[4];
    #pragma unroll
    for (int i=0;i<4;i++){
      unsigned short mybf = f2bf(hnew[i]);
      unsigned short ot = (unsigned short)__shfl_xor((int)mybf, 1, 64);
      packed[i] = (unsigned int)mybf | ((unsigned int)ot << 16);
    }
    unsigned int* hw = hb + ((ts+1)&1)*64*256;
    if ((l & 1) == 0){
      #pragma unroll
      for (int i=0;i<4;i++){
        int b = m0 + lg*4 + i;
        __hip_atomic_store(hw + b*256 + (jg>>1), packed[i], __ATOMIC_RELAXED, AGENT);
      }
    }
    __syncthreads();                       // all waves' h-stores drained (vmcnt 0 before barrier)
    if (tid == 0)
      __hip_atomic_store(fmine, (unsigned int)(ts+1), __ATOMIC_RELAXED, AGENT);

    // ---- layer-0 output (off critical path, after the release) ----
    #pragma unroll
    for (int i=0;i<4;i++){
      int b = m0 + lg*4 + i;
      l0out[(size_t)(t*64+b)*1024 + dir*512 + jg] = f2bf(hnew[i]);
    }
  }
}

// ---------------- layer 1: fused input-proj + fwd recurrence; bwd is ONE step ----------------
// grid = 64 blocks: bid<32 fwd recurrence slices (j0=16n), bid>=32 bwd single-step slices
__launch_bounds__(256)
__global__ void k_gru1(const unsigned short* __restrict__ l0out,
                       const unsigned short* __restrict__ wih1,   // [2][1536][1024] bf16 (f,b)
                       const unsigned short* __restrict__ whh1f,  // [1536][512] bf16
                       const float* __restrict__ bih_f, const float* __restrict__ bhh_f,
                       const float* __restrict__ bih_b, const float* __restrict__ bhh_b,
                       float* __restrict__ l1cat,                 // [64][1024] f32
                       unsigned int* __restrict__ hbuf,           // [2][64][256] dwords
                       unsigned int* __restrict__ flags)          // 32 producer slots x 32 dwords
{
  int bid = blockIdx.x;
  int bwd = bid >= 32;
  int n = bwd ? bid - 32 : bid;
  int j0 = n*16;
  int tid = threadIdx.x;
  int w = tid>>6, l = tid&63;
  int m0 = w*16, lj = l&15, lg = l>>4;

  __shared__ unsigned char lds[48*2048 + 48*1024];
  unsigned char* wih_lds = lds;
  unsigned char* whh_lds = lds + 48*2048;
  const unsigned short* wih_g = wih1 + (bwd ? (size_t)G3*1024 : 0);

  for (int c = tid; c < 48*128; c += 256){
    int lr = c >> 7, c16 = c & 127;
    int g = lr >> 4, jl = lr & 15;
    int gr = g*512 + j0 + jl;
    uint4 v = *(const uint4*)(wih_g + (size_t)gr*1024 + c16*8);
    *(uint4*)(wih_lds + lr*2048 + ((c16*16) ^ ((lr&7)<<4))) = v;
  }
  if (!bwd){
    for (int c = tid; c < 48*64; c += 256){
      int lr = c >> 6, c16 = c & 63;
      int g = lr >> 4, jl = lr & 15;
      int gr = g*512 + j0 + jl;
      uint4 v = *(const uint4*)(whh1f + (size_t)gr*HDIM + c16*8);
      *(uint4*)(whh_lds + lr*1024 + ((c16*16) ^ ((lr&7)<<4))) = v;
    }
  }
  __syncthreads();

  int jg = j0 + lj;
  const float* bih = bwd ? bih_b : bih_f;
  const float* bhh = bwd ? bhh_b : bhh_f;
  float brz = bih[jg] + bhh[jg];
  float bzz = bih[512+jg] + bhh[512+jg];
  float bxn = bih[1024+jg];
  float bhn = bhh[1024+jg];

  if (bwd){
    // single step at t=999 with h0 = 0  (gh = b_hh)
    int t = T_LEN-1;
    f32x4 aR={0.f,0.f,0.f,0.f}, aZ={0.f,0.f,0.f,0.f}, aXN={0.f,0.f,0.f,0.f};
    const unsigned short* arow = l0out + (size_t)(t*64 + m0 + lj)*1024 + lg*8;
    #pragma unroll 8
    for (int kt=0; kt<32; kt++){
      short8 a = *(const short8*)(arow + kt*32);
      int lr0 = 0*16+lj, lr1 = 1*16+lj, lr2 = 2*16+lj;
      int co = kt*64 + lg*16;
      short8 b0 = *(const short8*)(wih_lds + lr0*2048 + (co ^ ((lr0&7)<<4)));
      short8 b1 = *(const short8*)(wih_lds + lr1*2048 + (co ^ ((lr1&7)<<4)));
      short8 b2 = *(const short8*)(wih_lds + lr2*2048 + (co ^ ((lr2&7)<<4)));
      aR = MFMA(a,b0,aR); aZ = MFMA(a,b1,aZ); aXN = MFMA(a,b2,aXN);
    }
    #pragma unroll
    for (int i=0;i<4;i++){
      float r = sigm(aR[i] + brz);
      float z = sigm(aZ[i] + bzz);
      float nn = tanh_f(aXN[i] + bxn + r*bhn);
      l1cat[(size_t)(m0 + lg*4 + i)*1024 + 512 + jg] = (1.0f - z)*nn;
    }
    return;
  }

  float hreg[4] = {0.f,0.f,0.f,0.f};
  unsigned int* fmine = flags + n*32;
  for (int ts = 0; ts < T_LEN; ts++){
    f32x4 aR={0.f,0.f,0.f,0.f}, aZ={0.f,0.f,0.f,0.f}, aXN={0.f,0.f,0.f,0.f}, aHN={0.f,0.f,0.f,0.f};
    const unsigned short* arow = l0out + (size_t)(ts*64 + m0 + lj)*1024 + lg*8;
    #pragma unroll 8
    for (int kt=0; kt<32; kt++){
      short8 a = *(const short8*)(arow + kt*32);
      int lr0 = 0*16+lj, lr1 = 1*16+lj, lr2 = 2*16+lj;
      int co = kt*64 + lg*16;
      short8 b0 = *(const short8*)(wih_lds + lr0*2048 + (co ^ ((lr0&7)<<4)));
      short8 b1 = *(const short8*)(wih_lds + lr1*2048 + (co ^ ((lr1&7)<<4)));
      short8 b2 = *(const short8*)(wih_lds + lr2*2048 + (co ^ ((lr2&7)<<4)));
      aR = MFMA(a,b0,aR); aZ = MFMA(a,b1,aZ); aXN = MFMA(a,b2,aXN);
    }
    if (ts > 0){
      if (w == 0) wave0_wait(flags, 32, (unsigned int)ts, l);
      __syncthreads();
    }
    const unsigned long long* hrow = (const unsigned long long*)hbuf
        + (((ts&1)*64*256 + (m0+lj)*256 + lg*4) >> 1);
    #pragma unroll
    for (int kt=0; kt<16; kt++){
      union { unsigned long long u[2]; short8 s; } cv;
      cv.u[0] = __hip_atomic_load(hrow + kt*8 + 0, __ATOMIC_RELAXED, AGENT);
      cv.u[1] = __hip_atomic_load(hrow + kt*8 + 1, __ATOMIC_RELAXED, AGENT);
      int lr0 = 0*16+lj, lr1 = 1*16+lj, lr2 = 2*16+lj;
      int co = kt*64 + lg*16;
      short8 b0 = *(const short8*)(whh_lds + lr0*1024 + (co ^ ((lr0&7)<<4)));
      short8 b1 = *(const short8*)(whh_lds + lr1*1024 + (co ^ ((lr1&7)<<4)));
      short8 b2 = *(const short8*)(whh_lds + lr2*1024 + (co ^ ((lr2&7)<<4)));
      aR = MFMA(cv.s,b0,aR); aZ = MFMA(cv.s,b1,aZ); aHN = MFMA(cv.s,b2,aHN);
    }
    float hnew[4];
    #pragma unroll
    for (int i=0;i<4;i++){
      float r = sigm(aR[i] + brz);
      float z = sigm(aZ[i] + bzz);
      float nn = tanh_f(aXN[i] + bxn + r*(aHN[i] + bhn));
      hnew[i] = (1.0f - z)*nn + z*hreg[i];
      hreg[i] = hnew[i];
    }
    if (ts < T_LEN-1){
      unsigned int packed[4];
      #pragma unroll
      for (int i=0;i<4;i++){
        unsigned short mybf = f2bf(hnew[i]);
        unsigned short ot = (unsigned short)__shfl_xor((int)mybf, 1, 64);
        packed[i] = (unsigned int)mybf | ((unsigned int)ot << 16);
      }
      unsigned int* hw = hbuf + ((ts+1)&1)*64*256;
      if ((l & 1) == 0){
        #pragma unroll
        for (int i=0;i<4;i++){
          int b = m0 + lg*4 + i;
          __hip_atomic_store(hw + b*256 + (jg>>1), packed[i], __ATOMIC_RELAXED, AGENT);
        }
      }
      __syncthreads();
      if (tid == 0)
        __hip_atomic_store(fmine, (unsigned int)(ts+1), __ATOMIC_RELAXED, AGENT);
    } else {
      #pragma unroll
      for (int i=0;i<4;i++)
        l1cat[(size_t)(m0 + lg*4 + i)*1024 + jg] = hnew[i];
    }
  }
}

// ---------------- final FC ----------------
__global__ void k_fc(const float* __restrict__ l1cat, const float* __restrict__ fcw,
                     const float* __restrict__ fcb, float* __restrict__ out){
  int idx = blockIdx.x*256 + threadIdx.x;
  if (idx >= 64*12) return;
  int b = idx / 12, o = idx % 12;
  float s = fcb[o];
  for (int k=0;k<1024;k++) s += l1cat[b*1024+k]*fcw[o*1024+k];
  out[idx] = s;
}

extern "C" void kernel_launch(void* const* d_in, const int* in_sizes, int n_in,
                              void* d_out, int out_size, void* d_ws, size_t ws_size,
                              hipStream_t stream){
  const float* x     = (const float*)d_in[0];
  const float* wih0f = (const float*)d_in[1];
  const float* whh0f = (const float*)d_in[2];
  const float* bih0f = (const float*)d_in[3];
  const float* bhh0f = (const float*)d_in[4];
  const float* wih0b = (const float*)d_in[5];
  const float* whh0b = (const float*)d_in[6];
  const float* bih0b = (const float*)d_in[7];
  const float* bhh0b = (const float*)d_in[8];
  const float* wih1f = (const float*)d_in[9];
  const float* whh1f = (const float*)d_in[10];
  const float* bih1f = (const float*)d_in[11];
  const float* bhh1f = (const float*)d_in[12];
  const float* wih1b = (const float*)d_in[13];
  const float* bih1b = (const float*)d_in[15];
  const float* bhh1b = (const float*)d_in[16];
  const float* fcw   = (const float*)d_in[17];
  const float* fcb   = (const float*)d_in[18];

  char* ws = (char*)d_ws;
  size_t off = 0;
  auto alloc = [&](size_t bytes)->void*{ void* p = ws + off; off = (off + bytes + 255) & ~(size_t)255; return p; };
  unsigned short* xT    = (unsigned short*)alloc((size_t)64000*96*2);
  unsigned short* whh0c = (unsigned short*)alloc((size_t)2*1536*512*2);
  unsigned short* wih0c = (unsigned short*)alloc((size_t)2*1536*96*2);
  unsigned short* wih1c = (unsigned short*)alloc((size_t)2*1536*1024*2);
  unsigned short* whh1c = (unsigned short*)alloc((size_t)1536*512*2);
  unsigned short* l0out = (unsigned short*)alloc((size_t)64000*1024*2);
  unsigned int*   hbB   = (unsigned int*)alloc((size_t)2*2*64*256*4);
  unsigned int*   hbD   = (unsigned int*)alloc((size_t)2*64*256*4);
  float*          l1cat = (float*)alloc((size_t)64*1024*4);
  unsigned int*   flg   = (unsigned int*)alloc((size_t)64*32*4);   // 64 slots x 128B

  if (off > ws_size){
    // workspace too small -> unambiguous sentinel instead of OOB writes
    k_sentinel<<<(out_size+255)/256,256,0,stream>>>((float*)d_out, out_size);
    return;
  }

  hipMemsetAsync(hbB, 0, (size_t)2*2*64*256*4, stream);
  hipMemsetAsync(hbD, 0, (size_t)2*64*256*4, stream);
  hipMemsetAsync(flg, 0, (size_t)64*32*4, stream);

  k_conv<<<3072,256,0,stream>>>(whh0f, whh0c, 786432);
  k_conv<<<3072,256,0,stream>>>(whh0b, whh0c+786432, 786432);
  k_conv_pad<<<576,256,0,stream>>>(wih0f, wih0c, 1536, 69, 96);
  k_conv_pad<<<576,256,0,stream>>>(wih0b, wih0c+1536*96, 1536, 69, 96);
  k_conv<<<6144,256,0,stream>>>(wih1f, wih1c, 1572864);
  k_conv<<<6144,256,0,stream>>>(wih1b, wih1c+1572864, 1572864);
  k_conv<<<3072,256,0,stream>>>(whh1f, whh1c, 786432);
  k_xpose<<<1024,64,0,stream>>>(x, xT);

  k_gru0<<<32,512,0,stream>>>(xT, whh0c, wih0c, bih0f,bhh0f,bih0b,bhh0b, l0out, hbB, flg);
  k_gru1<<<64,256,0,stream>>>(l0out, wih1c, whh1c, bih1f,bhh1f,bih1b,bhh1b, l1cat, hbD, flg+32*32);
  k_fc<<<3,256,0,stream>>>(l1cat, fcw, fcb, (float*)d_out);
}